// Round 10
// baseline (527.397 us; speedup 1.0000x reference)
//
#include <hip/hip_runtime.h>

#pragma clang fp contract(off)

#define BB 32
#define NN 8192
#define GG 256
#define KK 32

#define TFPS 512
#define JPF (NN / TFPS)  // 16 points per thread

// f32 max DPP stage. bound_ctrl=true -> invalid-source lanes read 0.0f, and
// fmax(self, 0) == self for our non-negative values, so no corruption.
template <int CTRL>
__device__ __forceinline__ float dppmax_f(float v) {
  const int o =
      __builtin_amdgcn_update_dpp(0, __float_as_int(v), CTRL, 0xF, 0xF, true);
  return fmaxf(v, __int_as_float(o));
}

// u32 max DPP stage. Invalid-source lanes read 0; max(self,0)==self. Safe.
template <int CTRL>
__device__ __forceinline__ unsigned dppmax_u(unsigned v) {
  const unsigned o =
      (unsigned)__builtin_amdgcn_update_dpp(0, (int)v, CTRL, 0xF, 0xF, true);
  return o > v ? o : v;
}

// ---------------- FPS: one block per batch, 512 threads ----------------
// Winner COORDS propagate through LDS slots (no pts[] array, no index lookup).
__global__ __launch_bounds__(TFPS, 1) void fps_kernel(const float* __restrict__ xyz,
                                                      float* __restrict__ out) {
#pragma clang fp contract(off)
  const int b = blockIdx.x;
  const int t = threadIdx.x;
  const int lane = t & 63;
  const int wave = t >> 6;  // 0..7
  const float* __restrict__ P = xyz + (size_t)b * NN * 3;

  __shared__ unsigned long long skey[2][8];  // per-wave winner keys, dbuf
  __shared__ float4 scrd[2][8];              // per-wave winner coords, dbuf

  float px[JPF], py[JPF], pz[JPF], md[JPF];
#pragma unroll
  for (int j = 0; j < JPF; ++j) {
    const int idx = t + j * TFPS;
    px[j] = P[idx * 3 + 0];
    py[j] = P[idx * 3 + 1];
    pz[j] = P[idx * 3 + 2];
    md[j] = __builtin_inff();
  }

  // center 0 = point 0 (uniform scalar loads, once)
  float cx = P[0], cy = P[1], cz = P[2];
  float sx = 0.f, sy = 0.f, sz = 0.f;  // thread t records center t
  if (t == 0) { sx = cx; sy = cy; sz = cz; }

  for (int i = 0; i < GG - 1; ++i) {
    // distance update; VALUE-only max tracking (10 ops/pt)
    float bv = -1.0f;
#pragma unroll
    for (int j = 0; j < JPF; ++j) {
      const float dx = px[j] - cx;
      const float dy = py[j] - cy;
      const float dz = pz[j] - cz;
      const float d = dx * dx + dy * dy + dz * dz;  // ((x2+y2)+z2), no FMA
      const float m = md[j] < d ? md[j] : d;
      md[j] = m;
      bv = fmaxf(bv, m);
    }

    // wave max value via 6 DPP stages -> lane 63 -> SGPR broadcast
    float v = bv;
    v = dppmax_f<0x121>(v);  // row_ror:1
    v = dppmax_f<0x122>(v);  // row_ror:2
    v = dppmax_f<0x124>(v);  // row_ror:4
    v = dppmax_f<0x128>(v);  // row_ror:8  -> row max in all lanes
    v = dppmax_f<0x142>(v);  // row_bcast15
    v = dppmax_f<0x143>(v);  // row_bcast31 -> lane 63 = wave max
    const unsigned Mw =
        (unsigned)__builtin_amdgcn_readlane(__float_as_int(v), 63);

    // first local j matching the wave max (valid only on candidate lanes)
    int fj = 0;
#pragma unroll
    for (int j = JPF - 1; j >= 0; --j)
      if (__float_as_uint(md[j]) == Mw) fj = j;
    const unsigned cbi = (__float_as_uint(bv) == Mw)
                             ? ~((unsigned)t + ((unsigned)fj << 9))  // fj*512
                             : 0u;

    // wave max of ~index (= min global index among candidates) -> lane 63
    unsigned r = cbi;
    r = dppmax_u<0x121>(r);
    r = dppmax_u<0x122>(r);
    r = dppmax_u<0x124>(r);
    r = dppmax_u<0x128>(r);
    r = dppmax_u<0x142>(r);
    r = dppmax_u<0x143>(r);
    const unsigned wIdx = (unsigned)__builtin_amdgcn_readlane((int)r, 63);

    // exactly one lane matches: it writes key + coords (plain ds_writes)
    if (cbi == wIdx) {
      skey[i & 1][wave] = ((unsigned long long)Mw << 32) | wIdx;
      scrd[i & 1][wave] = make_float4(px[fj], py[fj], pz[fj], 0.f);
    }
    __syncthreads();

    // block winner: 16 parallel uniform LDS reads, register select
    const unsigned long long* __restrict__ kk = skey[i & 1];
    const float4* __restrict__ cc = scrd[i & 1];
    unsigned long long bk = kk[0];
    float4 bc = cc[0];
#pragma unroll
    for (int k = 1; k < 8; ++k) {
      const unsigned long long e = kk[k];
      const float4 ec = cc[k];
      if (e > bk) { bk = e; bc = ec; }
    }
    cx = bc.x; cy = bc.y; cz = bc.z;
    if (t == i + 1) { sx = cx; sy = cy; sz = cz; }
  }

  // write all centers once (off the critical loop)
  if (t < GG) {
    float* __restrict__ co =
        out + (size_t)BB * GG * KK * 3 + ((size_t)b * GG + t) * 3;
    co[0] = sx; co[1] = sy; co[2] = sz;
  }
}

// ---------------- KNN + gather: 8 blocks per batch ----------------
// Two-pass (min-only, then recompute+compact): no d2r[128] register array.
__global__ __launch_bounds__(512, 1) void knn_kernel(const float* __restrict__ xyz,
                                                     float* __restrict__ out) {
#pragma clang fp contract(off)
  const int b = blockIdx.x >> 3;
  const int chunk = blockIdx.x & 7;
  const int t = threadIdx.x;
  const int lane = t & 63;
  const int wave = t >> 6;
  const float* __restrict__ P = xyz + (size_t)b * NN * 3;

  __shared__ float xs[NN], ys[NN], zs[NN];          // 96 KB SoA planes
  __shared__ unsigned long long cand[8][256];       // 16 KB per-wave candidates

  for (int pt = t; pt < NN; pt += 512) {
    xs[pt] = P[pt * 3 + 0];
    ys[pt] = P[pt * 3 + 1];
    zs[pt] = P[pt * 3 + 2];
  }
  __syncthreads();

  const float* __restrict__ cent = out + (size_t)BB * GG * KK * 3;

  for (int gi = 0; gi < 4; ++gi) {
    const int g = chunk * 32 + wave * 4 + gi;
    const float cx = cent[((size_t)b * GG + g) * 3 + 0];
    const float cy = cent[((size_t)b * GG + g) * 3 + 1];
    const float cz = cent[((size_t)b * GG + g) * 3 + 2];

    // Pass 1: per-lane min over 128 points (no storage)
    float mn = __builtin_inff();
#pragma unroll 8
    for (int j = 0; j < 128; ++j) {
      const int idx = lane + j * 64;
      const float dx = xs[idx] - cx;
      const float dy = ys[idx] - cy;
      const float dz = zs[idx] - cz;
      const float d2 = dx * dx + dy * dy + dz * dz;  // no FMA
      mn = fminf(mn, d2);
    }

    // threshold v = 32nd-smallest of the 64 per-lane minima (bitonic sort)
    float sm = mn;
#pragma unroll
    for (int k = 2; k <= 64; k <<= 1) {
#pragma unroll
      for (int j2 = k >> 1; j2 > 0; j2 >>= 1) {
        const float o = __shfl_xor(sm, j2, 64);
        const bool keepMin = (((lane & k) == 0) == ((lane & j2) == 0));
        sm = keepMin ? fminf(sm, o) : fmaxf(sm, o);
      }
    }
    const float v = __shfl(sm, 31, 64);
    const float vi = __uint_as_float(__float_as_uint(v) + 8);  // +8 ulp guard

    // Pass 2: recompute d2 (bit-identical), ballot-compact into LDS
    unsigned cnt = 0;
    unsigned long long* __restrict__ cb = cand[wave];
#pragma unroll 8
    for (int j = 0; j < 128; ++j) {
      const int idx = lane + j * 64;
      const float dx = xs[idx] - cx;
      const float dy = ys[idx] - cy;
      const float dz = zs[idx] - cz;
      const float d2 = dx * dx + dy * dy + dz * dz;  // no FMA
      const bool p = d2 <= vi;
      const unsigned long long mk = __ballot(p);
      if (p) {
        const unsigned off = cnt + (unsigned)__popcll(mk & ((1ull << lane) - 1));
        if (off < 256)
          cb[off] = ((unsigned long long)__float_as_uint(d2) << 32) |
                    (unsigned)idx;
      }
      cnt += (unsigned)__popcll(mk);
    }
    if (cnt > 256) cnt = 256;

    // Phase C: exact sort by (sqrtf(d2) float, idx) ascending
    auto conv = [](unsigned long long e) -> unsigned long long {
      const float d = sqrtf(__uint_as_float((unsigned)(e >> 32)));
      return ((unsigned long long)__float_as_uint(d) << 32) | (e & 0xFFFFFFFFull);
    };

    unsigned long long myk;
    if (cnt <= 64) {
      unsigned long long key = ~0ull;
      if ((unsigned)lane < cnt) key = conv(cb[lane]);
#pragma unroll
      for (int k = 2; k <= 64; k <<= 1) {
#pragma unroll
        for (int j2 = k >> 1; j2 > 0; j2 >>= 1) {
          const unsigned long long o = __shfl_xor(key, j2, 64);
          const bool keepMin = (((lane & k) == 0) == ((lane & j2) == 0));
          const unsigned long long lo = o < key ? o : key;
          const unsigned long long hi = o < key ? key : o;
          key = keepMin ? lo : hi;
        }
      }
      myk = key;
    } else {
      // rare fallback: up to 256 candidates, 32 rounds of wave-argmin
      unsigned long long k0 = ~0ull, k1 = ~0ull, k2 = ~0ull, k3 = ~0ull;
      if ((unsigned)lane < cnt)         k0 = conv(cb[lane]);
      if ((unsigned)(lane + 64) < cnt)  k1 = conv(cb[lane + 64]);
      if ((unsigned)(lane + 128) < cnt) k2 = conv(cb[lane + 128]);
      if ((unsigned)(lane + 192) < cnt) k3 = conv(cb[lane + 192]);
      unsigned long long got = ~0ull;
      for (int r = 0; r < 32; ++r) {
        unsigned long long m01 = k0 < k1 ? k0 : k1;
        unsigned long long m23 = k2 < k3 ? k2 : k3;
        unsigned long long m = m01 < m23 ? m01 : m23;
#pragma unroll
        for (int s = 32; s > 0; s >>= 1) {
          const unsigned long long o = __shfl_xor(m, s, 64);
          m = o < m ? o : m;
        }
        if (lane == r) got = m;
        if (k0 == m) k0 = ~0ull;
        else if (k1 == m) k1 = ~0ull;
        else if (k2 == m) k2 = ~0ull;
        else if (k3 == m) k3 = ~0ull;
      }
      myk = got;
    }

    // gather + recenter + store (lane = rank)
    if (lane < KK) {
      const unsigned idx = (unsigned)(myk & 0xFFFFFFFFull);
      const float ox = xs[idx] - cx;
      const float oy = ys[idx] - cy;
      const float oz = zs[idx] - cz;
      float* __restrict__ po = out + ((size_t)(((size_t)b * GG + g) * KK + lane)) * 3;
      po[0] = ox; po[1] = oy; po[2] = oz;
    }
  }
}

extern "C" void kernel_launch(void* const* d_in, const int* in_sizes, int n_in,
                              void* d_out, int out_size, void* d_ws, size_t ws_size,
                              hipStream_t stream) {
  const float* xyz = (const float*)d_in[0];
  float* out = (float*)d_out;
  fps_kernel<<<dim3(BB), dim3(TFPS), 0, stream>>>(xyz, out);
  knn_kernel<<<dim3(BB * 8), dim3(512), 0, stream>>>(xyz, out);
}

// Round 11
// 473.023 us; speedup vs baseline: 1.1149x; 1.1149x over previous
//
#include <hip/hip_runtime.h>

#pragma clang fp contract(off)

#define BB 32
#define NN 8192
#define GG 256
#define KK 32

#define TFPS 512
#define PRS 8  // float2 pairs per thread (16 points)

typedef float v2f __attribute__((ext_vector_type(2)));

// f32 max DPP stage. bound_ctrl=true -> invalid-source lanes read 0.0f, and
// fmax(self, 0) == self for our non-negative values, so no corruption.
template <int CTRL>
__device__ __forceinline__ float dppmax_f(float v) {
  const int o =
      __builtin_amdgcn_update_dpp(0, __float_as_int(v), CTRL, 0xF, 0xF, true);
  return fmaxf(v, __int_as_float(o));
}

// u32 max DPP stage. Invalid-source lanes read 0; max(self,0)==self. Safe.
template <int CTRL>
__device__ __forceinline__ unsigned dppmax_u(unsigned v) {
  const unsigned o =
      (unsigned)__builtin_amdgcn_update_dpp(0, (int)v, CTRL, 0xF, 0xF, true);
  return o > v ? o : v;
}

// ---------------- FPS: one block per batch, 512 threads ----------------
// Coords propagate through tiny LDS slots; NO runtime-indexed register arrays.
__global__ __launch_bounds__(TFPS, 1) void fps_kernel(const float* __restrict__ xyz,
                                                      float* __restrict__ out) {
#pragma clang fp contract(off)
  const int b = blockIdx.x;
  const int t = threadIdx.x;
  const int wave = t >> 6;  // 0..7
  const float* __restrict__ P = xyz + (size_t)b * NN * 3;

  __shared__ unsigned long long skey[2][8];  // per-wave winner keys, dbuf
  __shared__ float4 scrd[2][8];              // per-wave winner coords, dbuf

  // pair layout: pair k holds points t+(2k)*512 (x-half) and t+(2k+1)*512 (y)
  v2f px[PRS], py[PRS], pz[PRS], md[PRS];
#pragma unroll
  for (int k = 0; k < PRS; ++k) {
    const int i0 = t + (2 * k) * TFPS;
    const int i1 = i0 + TFPS;
    px[k] = (v2f){P[i0 * 3 + 0], P[i1 * 3 + 0]};
    py[k] = (v2f){P[i0 * 3 + 1], P[i1 * 3 + 1]};
    pz[k] = (v2f){P[i0 * 3 + 2], P[i1 * 3 + 2]};
    md[k] = (v2f){__builtin_inff(), __builtin_inff()};
  }

  // center 0 = point 0 (uniform scalar loads, once)
  float cx = P[0], cy = P[1], cz = P[2];
  float sx = 0.f, sy = 0.f, sz = 0.f;  // thread t records center t
  if (t == 0) { sx = cx; sy = cy; sz = cz; }

  for (int i = 0; i < GG - 1; ++i) {
    // packed distance update (per element: ((dx*dx+dy*dy)+dz*dz), no FMA)
    const v2f c2x = (v2f){cx, cx};
    const v2f c2y = (v2f){cy, cy};
    const v2f c2z = (v2f){cz, cz};
    v2f bv2 = (v2f){-1.0f, -1.0f};
#pragma unroll
    for (int k = 0; k < PRS; ++k) {
      const v2f dx = px[k] - c2x;
      const v2f dy = py[k] - c2y;
      const v2f dz = pz[k] - c2z;
      const v2f d = (dx * dx + dy * dy) + dz * dz;
      const v2f m = __builtin_elementwise_min(md[k], d);
      md[k] = m;
      bv2 = __builtin_elementwise_max(bv2, m);
    }
    const float bv = fmaxf(bv2.x, bv2.y);

    // wave max value via 6 DPP stages -> lane 63 -> SGPR broadcast
    float v = bv;
    v = dppmax_f<0x121>(v);  // row_ror:1
    v = dppmax_f<0x122>(v);  // row_ror:2
    v = dppmax_f<0x124>(v);  // row_ror:4
    v = dppmax_f<0x128>(v);  // row_ror:8
    v = dppmax_f<0x142>(v);  // row_bcast15
    v = dppmax_f<0x143>(v);  // row_bcast31 -> lane 63 = wave max
    const unsigned Mw =
        (unsigned)__builtin_amdgcn_readlane(__float_as_int(v), 63);

    // descending scan: first local j with md==Mw, coords picked with
    // COMPILE-TIME indices only (predicated selects, no scratch)
    int fj = 0;
    float wx = 0.f, wy = 0.f, wz = 0.f;
#pragma unroll
    for (int k = PRS - 1; k >= 0; --k) {
      if (__float_as_uint(md[k].y) == Mw) {
        fj = 2 * k + 1; wx = px[k].y; wy = py[k].y; wz = pz[k].y;
      }
      if (__float_as_uint(md[k].x) == Mw) {
        fj = 2 * k;     wx = px[k].x; wy = py[k].x; wz = pz[k].x;
      }
    }
    const unsigned cbi = (__float_as_uint(bv) == Mw)
                             ? ~((unsigned)t + ((unsigned)fj << 9))  // fj*512
                             : 0u;

    // wave max of ~index (= min global index among candidates) -> lane 63
    unsigned r = cbi;
    r = dppmax_u<0x121>(r);
    r = dppmax_u<0x122>(r);
    r = dppmax_u<0x124>(r);
    r = dppmax_u<0x128>(r);
    r = dppmax_u<0x142>(r);
    r = dppmax_u<0x143>(r);
    const unsigned wIdx = (unsigned)__builtin_amdgcn_readlane((int)r, 63);

    // exactly the winner lane writes key + coords (plain ds_writes)
    if (cbi == wIdx) {
      skey[i & 1][wave] = ((unsigned long long)Mw << 32) | wIdx;
      scrd[i & 1][wave] = make_float4(wx, wy, wz, 0.f);
    }
    __syncthreads();

    // block winner: 16 parallel uniform LDS reads, register select
    const unsigned long long* __restrict__ kk = skey[i & 1];
    const float4* __restrict__ cc = scrd[i & 1];
    unsigned long long bk = kk[0];
    float4 bc = cc[0];
#pragma unroll
    for (int k = 1; k < 8; ++k) {
      const unsigned long long e = kk[k];
      const float4 ec = cc[k];
      if (e > bk) { bk = e; bc = ec; }
    }
    cx = bc.x; cy = bc.y; cz = bc.z;
    if (t == i + 1) { sx = cx; sy = cy; sz = cz; }
  }

  // write all centers once (off the critical loop)
  if (t < GG) {
    float* __restrict__ co =
        out + (size_t)BB * GG * KK * 3 + ((size_t)b * GG + t) * 3;
    co[0] = sx; co[1] = sy; co[2] = sz;
  }
}

// ---------------- KNN + gather: 8 blocks per batch ----------------
// Two-pass (min-only, then recompute+compact): no d2r[128] register array.
__global__ __launch_bounds__(512, 1) void knn_kernel(const float* __restrict__ xyz,
                                                     float* __restrict__ out) {
#pragma clang fp contract(off)
  const int b = blockIdx.x >> 3;
  const int chunk = blockIdx.x & 7;
  const int t = threadIdx.x;
  const int lane = t & 63;
  const int wave = t >> 6;
  const float* __restrict__ P = xyz + (size_t)b * NN * 3;

  __shared__ float xs[NN], ys[NN], zs[NN];          // 96 KB SoA planes
  __shared__ unsigned long long cand[8][256];       // 16 KB per-wave candidates

  for (int pt = t; pt < NN; pt += 512) {
    xs[pt] = P[pt * 3 + 0];
    ys[pt] = P[pt * 3 + 1];
    zs[pt] = P[pt * 3 + 2];
  }
  __syncthreads();

  const float* __restrict__ cent = out + (size_t)BB * GG * KK * 3;

  for (int gi = 0; gi < 4; ++gi) {
    const int g = chunk * 32 + wave * 4 + gi;
    const float cx = cent[((size_t)b * GG + g) * 3 + 0];
    const float cy = cent[((size_t)b * GG + g) * 3 + 1];
    const float cz = cent[((size_t)b * GG + g) * 3 + 2];

    // Pass 1: per-lane min over 128 points (no storage)
    float mn = __builtin_inff();
#pragma unroll 8
    for (int j = 0; j < 128; ++j) {
      const int idx = lane + j * 64;
      const float dx = xs[idx] - cx;
      const float dy = ys[idx] - cy;
      const float dz = zs[idx] - cz;
      const float d2 = dx * dx + dy * dy + dz * dz;  // no FMA
      mn = fminf(mn, d2);
    }

    // threshold v = 32nd-smallest of the 64 per-lane minima (bitonic sort)
    float sm = mn;
#pragma unroll
    for (int k = 2; k <= 64; k <<= 1) {
#pragma unroll
      for (int j2 = k >> 1; j2 > 0; j2 >>= 1) {
        const float o = __shfl_xor(sm, j2, 64);
        const bool keepMin = (((lane & k) == 0) == ((lane & j2) == 0));
        sm = keepMin ? fminf(sm, o) : fmaxf(sm, o);
      }
    }
    const float v = __shfl(sm, 31, 64);
    const float vi = __uint_as_float(__float_as_uint(v) + 8);  // +8 ulp guard

    // Pass 2: recompute d2 (bit-identical), ballot-compact into LDS
    unsigned cnt = 0;
    unsigned long long* __restrict__ cb = cand[wave];
#pragma unroll 8
    for (int j = 0; j < 128; ++j) {
      const int idx = lane + j * 64;
      const float dx = xs[idx] - cx;
      const float dy = ys[idx] - cy;
      const float dz = zs[idx] - cz;
      const float d2 = dx * dx + dy * dy + dz * dz;  // no FMA
      const bool p = d2 <= vi;
      const unsigned long long mk = __ballot(p);
      if (p) {
        const unsigned off = cnt + (unsigned)__popcll(mk & ((1ull << lane) - 1));
        if (off < 256)
          cb[off] = ((unsigned long long)__float_as_uint(d2) << 32) |
                    (unsigned)idx;
      }
      cnt += (unsigned)__popcll(mk);
    }
    if (cnt > 256) cnt = 256;

    // Phase C: exact sort by (sqrtf(d2) float, idx) ascending
    auto conv = [](unsigned long long e) -> unsigned long long {
      const float d = sqrtf(__uint_as_float((unsigned)(e >> 32)));
      return ((unsigned long long)__float_as_uint(d) << 32) | (e & 0xFFFFFFFFull);
    };

    unsigned long long myk;
    if (cnt <= 64) {
      unsigned long long key = ~0ull;
      if ((unsigned)lane < cnt) key = conv(cb[lane]);
#pragma unroll
      for (int k = 2; k <= 64; k <<= 1) {
#pragma unroll
        for (int j2 = k >> 1; j2 > 0; j2 >>= 1) {
          const unsigned long long o = __shfl_xor(key, j2, 64);
          const bool keepMin = (((lane & k) == 0) == ((lane & j2) == 0));
          const unsigned long long lo = o < key ? o : key;
          const unsigned long long hi = o < key ? key : o;
          key = keepMin ? lo : hi;
        }
      }
      myk = key;
    } else {
      // rare fallback: up to 256 candidates, 32 rounds of wave-argmin
      unsigned long long k0 = ~0ull, k1 = ~0ull, k2 = ~0ull, k3 = ~0ull;
      if ((unsigned)lane < cnt)         k0 = conv(cb[lane]);
      if ((unsigned)(lane + 64) < cnt)  k1 = conv(cb[lane + 64]);
      if ((unsigned)(lane + 128) < cnt) k2 = conv(cb[lane + 128]);
      if ((unsigned)(lane + 192) < cnt) k3 = conv(cb[lane + 192]);
      unsigned long long got = ~0ull;
      for (int r = 0; r < 32; ++r) {
        unsigned long long m01 = k0 < k1 ? k0 : k1;
        unsigned long long m23 = k2 < k3 ? k2 : k3;
        unsigned long long m = m01 < m23 ? m01 : m23;
#pragma unroll
        for (int s = 32; s > 0; s >>= 1) {
          const unsigned long long o = __shfl_xor(m, s, 64);
          m = o < m ? o : m;
        }
        if (lane == r) got = m;
        if (k0 == m) k0 = ~0ull;
        else if (k1 == m) k1 = ~0ull;
        else if (k2 == m) k2 = ~0ull;
        else if (k3 == m) k3 = ~0ull;
      }
      myk = got;
    }

    // gather + recenter + store (lane = rank)
    if (lane < KK) {
      const unsigned idx = (unsigned)(myk & 0xFFFFFFFFull);
      const float ox = xs[idx] - cx;
      const float oy = ys[idx] - cy;
      const float oz = zs[idx] - cz;
      float* __restrict__ po = out + ((size_t)(((size_t)b * GG + g) * KK + lane)) * 3;
      po[0] = ox; po[1] = oy; po[2] = oz;
    }
  }
}

extern "C" void kernel_launch(void* const* d_in, const int* in_sizes, int n_in,
                              void* d_out, int out_size, void* d_ws, size_t ws_size,
                              hipStream_t stream) {
  const float* xyz = (const float*)d_in[0];
  float* out = (float*)d_out;
  fps_kernel<<<dim3(BB), dim3(TFPS), 0, stream>>>(xyz, out);
  knn_kernel<<<dim3(BB * 8), dim3(512), 0, stream>>>(xyz, out);
}

// Round 12
// 358.619 us; speedup vs baseline: 1.4706x; 1.3190x over previous
//
#include <hip/hip_runtime.h>

#pragma clang fp contract(off)

#define BB 32
#define NN 8192
#define GG 256
#define KK 32

#define TFPS 1024
#define JPF (NN / TFPS)  // 8 points per thread

// f32 max DPP stage. bound_ctrl=true -> invalid-source lanes read 0.0f, and
// fmax(self, 0) == self for our non-negative values, so no corruption.
template <int CTRL>
__device__ __forceinline__ float dppmax_f(float v) {
  const int o =
      __builtin_amdgcn_update_dpp(0, __float_as_int(v), CTRL, 0xF, 0xF, true);
  return fmaxf(v, __int_as_float(o));
}

// ---------------- FPS: one block per batch, 1024 threads ----------------
__global__ __launch_bounds__(TFPS, 1) void fps_kernel(const float* __restrict__ xyz,
                                                      float* __restrict__ out) {
#pragma clang fp contract(off)
  const int b = blockIdx.x;
  const int t = threadIdx.x;
  const int lane = t & 63;
  const int wave = t >> 6;  // 0..15
  const float* __restrict__ P = xyz + (size_t)b * NN * 3;

  __shared__ float4 pts[NN];           // 128 KB: 1 ds_read_b128 per broadcast
  __shared__ float wmax[2][16];        // per-wave max, double-buffered
  __shared__ unsigned winIdx[2];       // argmin-index slots, double-buffered

  float px[JPF], py[JPF], pz[JPF], md[JPF];
#pragma unroll
  for (int j = 0; j < JPF; ++j) {
    const int idx = t + j * TFPS;
    const float x = P[idx * 3 + 0];
    const float y = P[idx * 3 + 1];
    const float z = P[idx * 3 + 2];
    px[j] = x; py[j] = y; pz[j] = z;
    md[j] = __builtin_inff();
    pts[idx] = make_float4(x, y, z, 0.0f);
  }
  if (t == 0) { winIdx[0] = 0xFFFFFFFFu; winIdx[1] = 0xFFFFFFFFu; }
  __syncthreads();

  unsigned win = 0;      // first center = index 0
  unsigned mywin = 0;    // thread t<GG records the step-t winner

  for (int i = 0; i < GG; ++i) {
    if (t == i) mywin = win;
    if (i == GG - 1) break;

    // broadcast winner coords from LDS (single b128, uniform address)
    const float4 c = pts[win];
    const float cx = c.x, cy = c.y, cz = c.z;

    // distance update; VALUE-only max tracking (10 ops/pt)
    float bv = -1.0f;
#pragma unroll
    for (int j = 0; j < JPF; ++j) {
      const float dx = px[j] - cx;
      const float dy = py[j] - cy;
      const float dz = pz[j] - cz;
      const float d = dx * dx + dy * dy + dz * dz;  // ((x2+y2)+z2), no FMA
      const float m = md[j] < d ? md[j] : d;
      md[j] = m;
      bv = fmaxf(bv, m);
    }

    // level 1: 6-stage DPP wave max -> lane 63 writes one float
    float v = bv;
    v = dppmax_f<0x121>(v);  // row_ror:1
    v = dppmax_f<0x122>(v);  // row_ror:2
    v = dppmax_f<0x124>(v);  // row_ror:4
    v = dppmax_f<0x128>(v);  // row_ror:8  -> row max in all lanes
    v = dppmax_f<0x142>(v);  // row_bcast15
    v = dppmax_f<0x143>(v);  // row_bcast31 -> lane 63 = wave max
    if (lane == 63) wmax[i & 1][wave] = v;
    __syncthreads();  // barrier 1

    // reset the OTHER buffer's index slot for step i+1
    if (t == 0) winIdx[(i + 1) & 1] = 0xFFFFFFFFu;

    // level 2 (replicated, cheap): 16 wave-maxes via 4 uniform float4 reads
    const float4* __restrict__ rm4 = (const float4*)wmax[i & 1];
    const float4 a0 = rm4[0], a1 = rm4[1], a2 = rm4[2], a3 = rm4[3];
    const float m0 = fmaxf(fmaxf(a0.x, a0.y), fmaxf(a0.z, a0.w));
    const float m1 = fmaxf(fmaxf(a1.x, a1.y), fmaxf(a1.z, a1.w));
    const float m2 = fmaxf(fmaxf(a2.x, a2.y), fmaxf(a2.z, a2.w));
    const float m3 = fmaxf(fmaxf(a3.x, a3.y), fmaxf(a3.z, a3.w));
    const float M = fmaxf(fmaxf(m0, m1), fmaxf(m2, m3));
    const unsigned Mu = __float_as_uint(M);

    // index recovery: only waves holding the max enter (execz-skipped in
    // ~15/16 waves); first local j, then atomicMin of the global index
    if (__float_as_uint(bv) == Mu) {
      int fj = 0;
#pragma unroll
      for (int j = JPF - 1; j >= 0; --j)
        if (__float_as_uint(md[j]) == Mu) fj = j;
      atomicMin(&winIdx[i & 1], (unsigned)t + ((unsigned)fj << 10));  // fj*1024
    }
    __syncthreads();  // barrier 2

    win = winIdx[i & 1];
  }

  // write all centers once (off the critical loop)
  if (t < GG) {
    const float4 c = pts[mywin];
    float* __restrict__ co =
        out + (size_t)BB * GG * KK * 3 + ((size_t)b * GG + t) * 3;
    co[0] = c.x; co[1] = c.y; co[2] = c.z;
  }
}

// ---------------- KNN + gather: 8 blocks per batch ----------------
// Two-pass (min-only, then recompute+compact): no d2r[128] register array.
__global__ __launch_bounds__(512, 1) void knn_kernel(const float* __restrict__ xyz,
                                                     float* __restrict__ out) {
#pragma clang fp contract(off)
  const int b = blockIdx.x >> 3;
  const int chunk = blockIdx.x & 7;
  const int t = threadIdx.x;
  const int lane = t & 63;
  const int wave = t >> 6;
  const float* __restrict__ P = xyz + (size_t)b * NN * 3;

  __shared__ float xs[NN], ys[NN], zs[NN];          // 96 KB SoA planes
  __shared__ unsigned long long cand[8][256];       // 16 KB per-wave candidates

  for (int pt = t; pt < NN; pt += 512) {
    xs[pt] = P[pt * 3 + 0];
    ys[pt] = P[pt * 3 + 1];
    zs[pt] = P[pt * 3 + 2];
  }
  __syncthreads();

  const float* __restrict__ cent = out + (size_t)BB * GG * KK * 3;

  for (int gi = 0; gi < 4; ++gi) {
    const int g = chunk * 32 + wave * 4 + gi;
    const float cx = cent[((size_t)b * GG + g) * 3 + 0];
    const float cy = cent[((size_t)b * GG + g) * 3 + 1];
    const float cz = cent[((size_t)b * GG + g) * 3 + 2];

    // Pass 1: per-lane min over 128 points (no storage)
    float mn = __builtin_inff();
#pragma unroll 8
    for (int j = 0; j < 128; ++j) {
      const int idx = lane + j * 64;
      const float dx = xs[idx] - cx;
      const float dy = ys[idx] - cy;
      const float dz = zs[idx] - cz;
      const float d2 = dx * dx + dy * dy + dz * dz;  // no FMA
      mn = fminf(mn, d2);
    }

    // threshold v = 32nd-smallest of the 64 per-lane minima (bitonic sort)
    float sm = mn;
#pragma unroll
    for (int k = 2; k <= 64; k <<= 1) {
#pragma unroll
      for (int j2 = k >> 1; j2 > 0; j2 >>= 1) {
        const float o = __shfl_xor(sm, j2, 64);
        const bool keepMin = (((lane & k) == 0) == ((lane & j2) == 0));
        sm = keepMin ? fminf(sm, o) : fmaxf(sm, o);
      }
    }
    const float v = __shfl(sm, 31, 64);
    const float vi = __uint_as_float(__float_as_uint(v) + 8);  // +8 ulp guard

    // Pass 2: recompute d2 (bit-identical), ballot-compact into LDS
    unsigned cnt = 0;
    unsigned long long* __restrict__ cb = cand[wave];
#pragma unroll 8
    for (int j = 0; j < 128; ++j) {
      const int idx = lane + j * 64;
      const float dx = xs[idx] - cx;
      const float dy = ys[idx] - cy;
      const float dz = zs[idx] - cz;
      const float d2 = dx * dx + dy * dy + dz * dz;  // no FMA
      const bool p = d2 <= vi;
      const unsigned long long mk = __ballot(p);
      if (p) {
        const unsigned off = cnt + (unsigned)__popcll(mk & ((1ull << lane) - 1));
        if (off < 256)
          cb[off] = ((unsigned long long)__float_as_uint(d2) << 32) |
                    (unsigned)idx;
      }
      cnt += (unsigned)__popcll(mk);
    }
    if (cnt > 256) cnt = 256;

    // Phase C: exact sort by (sqrtf(d2) float, idx) ascending
    auto conv = [](unsigned long long e) -> unsigned long long {
      const float d = sqrtf(__uint_as_float((unsigned)(e >> 32)));
      return ((unsigned long long)__float_as_uint(d) << 32) | (e & 0xFFFFFFFFull);
    };

    unsigned long long myk;
    if (cnt <= 64) {
      unsigned long long key = ~0ull;
      if ((unsigned)lane < cnt) key = conv(cb[lane]);
#pragma unroll
      for (int k = 2; k <= 64; k <<= 1) {
#pragma unroll
        for (int j2 = k >> 1; j2 > 0; j2 >>= 1) {
          const unsigned long long o = __shfl_xor(key, j2, 64);
          const bool keepMin = (((lane & k) == 0) == ((lane & j2) == 0));
          const unsigned long long lo = o < key ? o : key;
          const unsigned long long hi = o < key ? key : o;
          key = keepMin ? lo : hi;
        }
      }
      myk = key;
    } else {
      // rare fallback: up to 256 candidates, 32 rounds of wave-argmin
      unsigned long long k0 = ~0ull, k1 = ~0ull, k2 = ~0ull, k3 = ~0ull;
      if ((unsigned)lane < cnt)         k0 = conv(cb[lane]);
      if ((unsigned)(lane + 64) < cnt)  k1 = conv(cb[lane + 64]);
      if ((unsigned)(lane + 128) < cnt) k2 = conv(cb[lane + 128]);
      if ((unsigned)(lane + 192) < cnt) k3 = conv(cb[lane + 192]);
      unsigned long long got = ~0ull;
      for (int r = 0; r < 32; ++r) {
        unsigned long long m01 = k0 < k1 ? k0 : k1;
        unsigned long long m23 = k2 < k3 ? k2 : k3;
        unsigned long long m = m01 < m23 ? m01 : m23;
#pragma unroll
        for (int s = 32; s > 0; s >>= 1) {
          const unsigned long long o = __shfl_xor(m, s, 64);
          m = o < m ? o : m;
        }
        if (lane == r) got = m;
        if (k0 == m) k0 = ~0ull;
        else if (k1 == m) k1 = ~0ull;
        else if (k2 == m) k2 = ~0ull;
        else if (k3 == m) k3 = ~0ull;
      }
      myk = got;
    }

    // gather + recenter + store (lane = rank)
    if (lane < KK) {
      const unsigned idx = (unsigned)(myk & 0xFFFFFFFFull);
      const float ox = xs[idx] - cx;
      const float oy = ys[idx] - cy;
      const float oz = zs[idx] - cz;
      float* __restrict__ po = out + ((size_t)(((size_t)b * GG + g) * KK + lane)) * 3;
      po[0] = ox; po[1] = oy; po[2] = oz;
    }
  }
}

extern "C" void kernel_launch(void* const* d_in, const int* in_sizes, int n_in,
                              void* d_out, int out_size, void* d_ws, size_t ws_size,
                              hipStream_t stream) {
  const float* xyz = (const float*)d_in[0];
  float* out = (float*)d_out;
  fps_kernel<<<dim3(BB), dim3(TFPS), 0, stream>>>(xyz, out);
  knn_kernel<<<dim3(BB * 8), dim3(512), 0, stream>>>(xyz, out);
}

// Round 14
// 319.176 us; speedup vs baseline: 1.6524x; 1.1236x over previous
//
#include <hip/hip_runtime.h>

#pragma clang fp contract(off)

#define BB 32
#define NN 8192
#define GG 256
#define KK 32

#define TFPS 512
#define JPF (NN / TFPS)  // 16 points per thread

// f32 max over a 16-lane row via DPP row_ror (pure VALU).
template <int CTRL>
__device__ __forceinline__ float rot_maxf(float v) {
  const int o =
      __builtin_amdgcn_update_dpp(0, __float_as_int(v), CTRL, 0xF, 0xF, true);
  return fmaxf(v, __int_as_float(o));
}

// ---------------- FPS: one block per batch, 512 threads (R7 verbatim) -----
__global__ __launch_bounds__(TFPS, 1) void fps_kernel(const float* __restrict__ xyz,
                                                      float* __restrict__ out) {
#pragma clang fp contract(off)
  const int b = blockIdx.x;
  const int t = threadIdx.x;
  const int lane = t & 63;
  const int wave = t >> 6;  // 0..7
  const float* __restrict__ P = xyz + (size_t)b * NN * 3;

  __shared__ float4 pts[NN];          // 128 KB: 1 ds_read_b128 per broadcast
  __shared__ float rowmax[2][32];     // 8 waves x 4 rows, double-buffered
  __shared__ unsigned winIdx[2];      // argmin-index slots, double-buffered

  float px[JPF], py[JPF], pz[JPF], md[JPF];
#pragma unroll
  for (int j = 0; j < JPF; ++j) {
    const int idx = t + j * TFPS;
    const float x = P[idx * 3 + 0];
    const float y = P[idx * 3 + 1];
    const float z = P[idx * 3 + 2];
    px[j] = x; py[j] = y; pz[j] = z;
    md[j] = __builtin_inff();
    pts[idx] = make_float4(x, y, z, 0.0f);
  }
  if (t == 0) { winIdx[0] = 0xFFFFFFFFu; winIdx[1] = 0xFFFFFFFFu; }
  __syncthreads();

  unsigned win = 0;      // first center = index 0
  unsigned mywin = 0;    // thread t<GG records the step-t winner

  for (int i = 0; i < GG; ++i) {
    if (t == i) mywin = win;
    if (i == GG - 1) break;

    // broadcast winner coords from LDS (single b128, uniform address)
    const float4 c = pts[win];
    const float cx = c.x, cy = c.y, cz = c.z;

    // distance update; track only the VALUE of the local max (no index ops)
    float bv = -1.0f;
#pragma unroll
    for (int j = 0; j < JPF; ++j) {
      const float dx = px[j] - cx;
      const float dy = py[j] - cy;
      const float dz = pz[j] - cz;
      const float d = dx * dx + dy * dy + dz * dz;  // ((x2+y2)+z2), no FMA
      const float m = md[j] < d ? md[j] : d;
      md[j] = m;
      bv = fmaxf(bv, m);
    }

    // level 1: 16-lane row max via DPP rotations (f32 only)
    float r = bv;
    r = rot_maxf<0x121>(r);  // ror 1
    r = rot_maxf<0x122>(r);  // ror 2
    r = rot_maxf<0x124>(r);  // ror 4
    r = rot_maxf<0x128>(r);  // ror 8
    if ((lane & 15) == 0)
      rowmax[i & 1][wave * 4 + (lane >> 4)] = r;
    __syncthreads();  // barrier 1

    // reset the OTHER buffer's index slot for step i+1
    if (t == 0) winIdx[(i + 1) & 1] = 0xFFFFFFFFu;

    // level 2: 32 row-maxes -> global max M in every lane (f32 only)
    const float* __restrict__ rm = rowmax[i & 1];
    const int g = lane & 15;
    float m2 = fmaxf(rm[g], rm[g + 16]);
    m2 = rot_maxf<0x121>(m2);
    m2 = rot_maxf<0x122>(m2);
    m2 = rot_maxf<0x124>(m2);
    m2 = rot_maxf<0x128>(m2);
    const float M = m2;

    // index recovery: only threads holding the max rescan (execz-skipped in
    // waves with no candidate); smallest global index wins (== first argmax)
    if (bv == M) {
      int fj = 0;
#pragma unroll
      for (int j = JPF - 1; j >= 0; --j)
        if (md[j] == M) fj = j;
      atomicMin(&winIdx[i & 1], (unsigned)t + ((unsigned)fj << 9));  // fj*512
    }
    __syncthreads();  // barrier 2

    win = winIdx[i & 1];
  }

  // write all centers once (off the critical loop)
  if (t < GG) {
    const float4 c = pts[mywin];
    float* __restrict__ co =
        out + (size_t)BB * GG * KK * 3 + ((size_t)b * GG + t) * 3;
    co[0] = c.x; co[1] = c.y; co[2] = c.z;
  }
}

// ---------------- KNN + gather: 8 blocks per batch ----------------
// float4 LDS staging (1 b128/point) + pass-1 fused across the wave's 4 groups.
__global__ __launch_bounds__(512, 1) void knn_kernel(const float* __restrict__ xyz,
                                                     float* __restrict__ out) {
#pragma clang fp contract(off)
  const int b = blockIdx.x >> 3;
  const int chunk = blockIdx.x & 7;
  const int t = threadIdx.x;
  const int lane = t & 63;
  const int wave = t >> 6;
  const float* __restrict__ P = xyz + (size_t)b * NN * 3;

  __shared__ float4 pts4[NN];                       // 128 KB
  __shared__ unsigned long long cand[8][256];       // 16 KB per-wave buffer

  for (int pt = t; pt < NN; pt += 512)
    pts4[pt] = make_float4(P[pt * 3 + 0], P[pt * 3 + 1], P[pt * 3 + 2], 0.0f);
  __syncthreads();

  const float* __restrict__ cent = out + (size_t)BB * GG * KK * 3;
  const int gbase = chunk * 32 + wave * 4;

  // load the wave's 4 centers into named scalars (compile-time indices only)
  const float c0x = cent[((size_t)b * GG + gbase + 0) * 3 + 0];
  const float c0y = cent[((size_t)b * GG + gbase + 0) * 3 + 1];
  const float c0z = cent[((size_t)b * GG + gbase + 0) * 3 + 2];
  const float c1x = cent[((size_t)b * GG + gbase + 1) * 3 + 0];
  const float c1y = cent[((size_t)b * GG + gbase + 1) * 3 + 1];
  const float c1z = cent[((size_t)b * GG + gbase + 1) * 3 + 2];
  const float c2x = cent[((size_t)b * GG + gbase + 2) * 3 + 0];
  const float c2y = cent[((size_t)b * GG + gbase + 2) * 3 + 1];
  const float c2z = cent[((size_t)b * GG + gbase + 2) * 3 + 2];
  const float c3x = cent[((size_t)b * GG + gbase + 3) * 3 + 0];
  const float c3y = cent[((size_t)b * GG + gbase + 3) * 3 + 1];
  const float c3z = cent[((size_t)b * GG + gbase + 3) * 3 + 2];

  // Pass 1 (fused): one sweep, 4 running minima
  float mn0 = __builtin_inff(), mn1 = __builtin_inff();
  float mn2 = __builtin_inff(), mn3 = __builtin_inff();
#pragma unroll 4
  for (int j = 0; j < 128; ++j) {
    const float4 p = pts4[lane + j * 64];
    {
      const float dx = p.x - c0x, dy = p.y - c0y, dz = p.z - c0z;
      mn0 = fminf(mn0, dx * dx + dy * dy + dz * dz);
    }
    {
      const float dx = p.x - c1x, dy = p.y - c1y, dz = p.z - c1z;
      mn1 = fminf(mn1, dx * dx + dy * dy + dz * dz);
    }
    {
      const float dx = p.x - c2x, dy = p.y - c2y, dz = p.z - c2z;
      mn2 = fminf(mn2, dx * dx + dy * dy + dz * dz);
    }
    {
      const float dx = p.x - c3x, dy = p.y - c3y, dz = p.z - c3z;
      mn3 = fminf(mn3, dx * dx + dy * dy + dz * dz);
    }
  }

  // threshold = 32nd-smallest of the 64 per-lane minima (+8 ulp guard)
  auto thresh = [&](float mn) -> float {
    float sm = mn;
#pragma unroll
    for (int k = 2; k <= 64; k <<= 1) {
#pragma unroll
      for (int j2 = k >> 1; j2 > 0; j2 >>= 1) {
        const float o = __shfl_xor(sm, j2, 64);
        const bool keepMin = (((lane & k) == 0) == ((lane & j2) == 0));
        sm = keepMin ? fminf(sm, o) : fmaxf(sm, o);
      }
    }
    const float v = __shfl(sm, 31, 64);
    return __uint_as_float(__float_as_uint(v) + 8);
  };
  const float vi0 = thresh(mn0);
  const float vi1 = thresh(mn1);
  const float vi2 = thresh(mn2);
  const float vi3 = thresh(mn3);

  // Pass 2 per group: recompute d2 (bit-identical), compact, sort, store
  auto dogroup = [&](int g, float cx, float cy, float cz, float vi) {
    unsigned cnt = 0;
    unsigned long long* __restrict__ cb = cand[wave];
#pragma unroll 4
    for (int j = 0; j < 128; ++j) {
      const int idx = lane + j * 64;
      const float4 p = pts4[idx];
      const float dx = p.x - cx, dy = p.y - cy, dz = p.z - cz;
      const float d2 = dx * dx + dy * dy + dz * dz;  // no FMA
      const bool pr = d2 <= vi;
      const unsigned long long mk = __ballot(pr);
      if (pr) {
        const unsigned off = cnt + (unsigned)__popcll(mk & ((1ull << lane) - 1));
        if (off < 256)
          cb[off] = ((unsigned long long)__float_as_uint(d2) << 32) |
                    (unsigned)idx;
      }
      cnt += (unsigned)__popcll(mk);
    }
    if (cnt > 256) cnt = 256;

    auto conv = [](unsigned long long e) -> unsigned long long {
      const float d = sqrtf(__uint_as_float((unsigned)(e >> 32)));
      return ((unsigned long long)__float_as_uint(d) << 32) | (e & 0xFFFFFFFFull);
    };

    unsigned long long myk;
    if (cnt <= 64) {
      unsigned long long key = ~0ull;
      if ((unsigned)lane < cnt) key = conv(cb[lane]);
#pragma unroll
      for (int k = 2; k <= 64; k <<= 1) {
#pragma unroll
        for (int j2 = k >> 1; j2 > 0; j2 >>= 1) {
          const unsigned long long o = __shfl_xor(key, j2, 64);
          const bool keepMin = (((lane & k) == 0) == ((lane & j2) == 0));
          const unsigned long long lo = o < key ? o : key;
          const unsigned long long hi = o < key ? key : o;
          key = keepMin ? lo : hi;
        }
      }
      myk = key;
    } else {
      // rare fallback: up to 256 candidates, 32 rounds of wave-argmin
      unsigned long long k0 = ~0ull, k1 = ~0ull, k2 = ~0ull, k3 = ~0ull;
      if ((unsigned)lane < cnt)         k0 = conv(cb[lane]);
      if ((unsigned)(lane + 64) < cnt)  k1 = conv(cb[lane + 64]);
      if ((unsigned)(lane + 128) < cnt) k2 = conv(cb[lane + 128]);
      if ((unsigned)(lane + 192) < cnt) k3 = conv(cb[lane + 192]);
      unsigned long long got = ~0ull;
      for (int r = 0; r < 32; ++r) {
        unsigned long long m01 = k0 < k1 ? k0 : k1;
        unsigned long long m23 = k2 < k3 ? k2 : k3;
        unsigned long long m = m01 < m23 ? m01 : m23;
#pragma unroll
        for (int s = 32; s > 0; s >>= 1) {
          const unsigned long long o = __shfl_xor(m, s, 64);
          m = o < m ? o : m;
        }
        if (lane == r) got = m;
        if (k0 == m) k0 = ~0ull;
        else if (k1 == m) k1 = ~0ull;
        else if (k2 == m) k2 = ~0ull;
        else if (k3 == m) k3 = ~0ull;
      }
      myk = got;
    }

    if (lane < KK) {
      const unsigned idx = (unsigned)(myk & 0xFFFFFFFFull);
      const float4 p = pts4[idx];
      float* __restrict__ po =
          out + ((size_t)(((size_t)b * GG + g) * KK + lane)) * 3;
      po[0] = p.x - cx; po[1] = p.y - cy; po[2] = p.z - cz;
    }
  };

  dogroup(gbase + 0, c0x, c0y, c0z, vi0);
  dogroup(gbase + 1, c1x, c1y, c1z, vi1);
  dogroup(gbase + 2, c2x, c2y, c2z, vi2);
  dogroup(gbase + 3, c3x, c3y, c3z, vi3);
}

extern "C" void kernel_launch(void* const* d_in, const int* in_sizes, int n_in,
                              void* d_out, int out_size, void* d_ws, size_t ws_size,
                              hipStream_t stream) {
  const float* xyz = (const float*)d_in[0];
  float* out = (float*)d_out;
  fps_kernel<<<dim3(BB), dim3(TFPS), 0, stream>>>(xyz, out);
  knn_kernel<<<dim3(BB * 8), dim3(512), 0, stream>>>(xyz, out);
}